// Round 5
// baseline (1292.247 us; speedup 1.0000x reference)
//
#include <hip/hip_runtime.h>
#include <math.h>

#define NNODES 100000
#define NEDGES 1600000
#define NREL   4
#define DIN    38
#define HID    64
#define NGRAPH 1000
#define NSEG   (NNODES * NREL)          // 400000
#define NSCANB ((NSEG + 1023) / 1024)   // 391

// ---------------------------------------------------------------------------
// counts: cnt[node*R+rel] edge counts, gcnt[g] nodes per graph
// ---------------------------------------------------------------------------
__global__ __launch_bounds__(256) void count_kernel(
    const int* __restrict__ ei, const int* __restrict__ et,
    const int* __restrict__ batch, int* __restrict__ cnt,
    int* __restrict__ gcnt) {
    int i = blockIdx.x * 256 + threadIdx.x;
    if (i < NEDGES) {
        int dst = ei[NEDGES + i];
        atomicAdd(&cnt[dst * NREL + et[i]], 1);
    }
    if (i < NNODES) {
        atomicAdd(&gcnt[batch[i]], 1);
    }
}

// ---------------------------------------------------------------------------
// scan1: per-1024-chunk exclusive scan of cnt -> excl, chunk totals -> bsum
// ---------------------------------------------------------------------------
__global__ __launch_bounds__(256) void scan1_kernel(
    const int* __restrict__ cnt, int* __restrict__ excl, int* __restrict__ bsum) {
    __shared__ int tmp[256];
    int tid = threadIdx.x;
    int base = blockIdx.x * 1024 + tid * 4;
    int v0 = 0, v1 = 0, v2 = 0, v3 = 0;
    if (base + 0 < NSEG) v0 = cnt[base + 0];
    if (base + 1 < NSEG) v1 = cnt[base + 1];
    if (base + 2 < NSEG) v2 = cnt[base + 2];
    if (base + 3 < NSEG) v3 = cnt[base + 3];
    int s = v0 + v1 + v2 + v3;
    tmp[tid] = s;
    __syncthreads();
    for (int off = 1; off < 256; off <<= 1) {
        int t = (tid >= off) ? tmp[tid - off] : 0;
        __syncthreads();
        tmp[tid] += t;
        __syncthreads();
    }
    if (tid == 255) bsum[blockIdx.x] = tmp[255];
    int run = tmp[tid] - s;
    if (base + 0 < NSEG) excl[base + 0] = run; run += v0;
    if (base + 1 < NSEG) excl[base + 1] = run; run += v1;
    if (base + 2 < NSEG) excl[base + 2] = run; run += v2;
    if (base + 3 < NSEG) excl[base + 3] = run;
}

// scan2: exclusive scan of bsum[NSCANB] in one block
__global__ __launch_bounds__(512) void scan2_kernel(int* __restrict__ bsum) {
    __shared__ int tmp[512];
    int tid = threadIdx.x;
    int v = (tid < NSCANB) ? bsum[tid] : 0;
    tmp[tid] = v;
    __syncthreads();
    for (int off = 1; off < 512; off <<= 1) {
        int t = (tid >= off) ? tmp[tid - off] : 0;
        __syncthreads();
        tmp[tid] += t;
        __syncthreads();
    }
    if (tid < NSCANB) bsum[tid] = tmp[tid] - v;
}

// ---------------------------------------------------------------------------
// place: CSR bucket fill. packed entry = src | (rel << 20)
// ---------------------------------------------------------------------------
__global__ __launch_bounds__(256) void place_kernel(
    const int* __restrict__ ei, const int* __restrict__ et,
    const int* __restrict__ excl, const int* __restrict__ bsum,
    int* __restrict__ fill, int* __restrict__ esrc) {
    int e = blockIdx.x * 256 + threadIdx.x;
    if (e >= NEDGES) return;
    int r = et[e];
    int seg = ei[NEDGES + e] * NREL + r;
    int pos = excl[seg] + bsum[seg >> 10] + atomicAdd(&fill[seg], 1);
    esrc[pos] = ei[e] | (r << 20);
}

__device__ __forceinline__ void ln_group_reduce(float& s) {
    s += __shfl_xor(s, 1);
    s += __shfl_xor(s, 2);
    s += __shfl_xor(s, 4);
    s += __shfl_xor(s, 8);
}

template <int K>
__device__ __forceinline__ void gemm_acc(const float (*As)[68], const float (*Ws)[68],
                                         int r, int c, float acc[4][4]) {
    #pragma unroll 2
    for (int k = 0; k < K; ++k) {
        const float4 av = *(const float4*)&As[k][r * 4];
        const float4 wv = *(const float4*)&Ws[k][c * 4];
        const float a_[4] = {av.x, av.y, av.z, av.w};
        const float w_[4] = {wv.x, wv.y, wv.z, wv.w};
        #pragma unroll
        for (int i = 0; i < 4; ++i)
            #pragma unroll
            for (int j = 0; j < 4; ++j)
                acc[i][j] += a_[i] * w_[j];
    }
}

// ---------------------------------------------------------------------------
// fused layer kernel: 64-node tile per block, 256 threads (4 waves).
// Phase 1: per-wave serial gather of per-(node,rel) means of x[src] into regs
//          (lane = channel, 16 nodes/wave, 4 rel accumulators each).
// Phase 2: 4 relation GEMM passes + root pass (+res pass if L0), K=F each,
//          A from LDS (means / x-tile), W from LDS, 4x4 register micro-tile.
// Epilogue: relu(conv+bias) + residual (+resb if L0), LayerNorm over 64 ch
//          (16-lane groups). POOL: atomicAdd into pooled[batch[n]].
// ---------------------------------------------------------------------------
template <int F, bool L0, bool POOL>
__global__ __launch_bounds__(256, 4) void fused_kernel(
    const float* __restrict__ x, const float* __restrict__ W,
    const float* __restrict__ root, const float* __restrict__ resw,
    const float* __restrict__ bias, const float* __restrict__ resb,
    const float* __restrict__ lng, const float* __restrict__ lnb,
    const int* __restrict__ cnt, const int* __restrict__ excl,
    const int* __restrict__ bsum, const int* __restrict__ esrc,
    const int* __restrict__ batch, float* __restrict__ dst) {
    __shared__ float As[64][68];
    __shared__ float Ws[64][68];
    int tid = threadIdx.x;
    int nbase = blockIdx.x * 64;
    int wv = tid >> 6, lane = tid & 63;

    // ---- phase 1: gather per-relation means into registers ----
    float mreg[16][4];
    #pragma unroll
    for (int j = 0; j < 16; ++j) {
        int n = nbase + wv * 16 + j;
        if (n > NNODES - 1) n = NNODES - 1;
        int s4 = n * 4;
        int myc = 0, myb = 0;
        if (lane < 4) {
            myc = cnt[s4 + lane];
            myb = excl[s4 + lane] + bsum[(s4 + lane) >> 10];
        }
        int c0 = __shfl(myc, 0), c1 = __shfl(myc, 1);
        int c2 = __shfl(myc, 2), c3 = __shfl(myc, 3);
        int beg = __shfl(myb, 0);
        int ctot = c0 + c1 + c2 + c3;
        float a0 = 0.f, a1 = 0.f, a2 = 0.f, a3 = 0.f;
        for (int base = 0; base < ctot; base += 64) {
            int rem = ctot - base; if (rem > 64) rem = 64;
            int ev = (lane < rem) ? esrc[beg + base + lane] : 0;
            for (int i = 0; i < rem; ++i) {
                int raw = __shfl(ev, i);
                int src = raw & 0xFFFFF;
                int rr = raw >> 20;
                float v = 0.f;
                if (F == 64 || lane < F) v = x[(size_t)src * F + lane];
                if (rr == 0)      a0 += v;
                else if (rr == 1) a1 += v;
                else if (rr == 2) a2 += v;
                else              a3 += v;
            }
        }
        mreg[j][0] = a0 / fmaxf((float)c0, 1.f);
        mreg[j][1] = a1 / fmaxf((float)c1, 1.f);
        mreg[j][2] = a2 / fmaxf((float)c2, 1.f);
        mreg[j][3] = a3 / fmaxf((float)c3, 1.f);
    }

    int r = tid >> 4, c = tid & 15;
    float acc[4][4] = {};
    float accB[4][4] = {};

    // ---- phase 2a: 4 relation GEMM passes ----
    #pragma unroll
    for (int rel = 0; rel < 4; ++rel) {
        __syncthreads();   // previous pass done reading As/Ws
        // write means into As (k = channel = lane, m = node-local)
        #pragma unroll
        for (int j = 0; j < 16; ++j)
            if (F == 64 || lane < F) As[lane][wv * 16 + j] = mreg[j][rel];
        // stage Ws = W[rel] ([F][64] row-major)
        const float* wsrc = W + (size_t)rel * F * 64;
        if (F == 64) {
            int scc = tid & 63, sk0 = tid >> 6;
            #pragma unroll
            for (int kk = 0; kk < 16; ++kk) {
                int k = sk0 + kk * 4;
                Ws[k][scc] = wsrc[k * 64 + scc];
            }
        } else {
            for (int idx = tid; idx < F * 64; idx += 256)
                Ws[idx >> 6][idx & 63] = wsrc[idx];
        }
        __syncthreads();
        gemm_acc<F>(As, Ws, r, c, acc);
    }

    // ---- phase 2b: root pass (As = x tile, Ws = root) ----
    __syncthreads();
    if (F == 64) {
        int sk = tid & 63, sm0 = tid >> 6;
        #pragma unroll
        for (int mm = 0; mm < 16; ++mm) {
            int m = sm0 + mm * 4;
            int n = nbase + m; if (n > NNODES - 1) n = NNODES - 1;
            As[sk][m] = x[(size_t)n * 64 + sk];
        }
        int scc = tid & 63, sk0 = tid >> 6;
        #pragma unroll
        for (int kk = 0; kk < 16; ++kk) {
            int k = sk0 + kk * 4;
            Ws[k][scc] = root[k * 64 + scc];
        }
    } else {
        for (int idx = tid; idx < 64 * F; idx += 256) {
            int m = idx / F, k = idx - m * F;
            int n = nbase + m; if (n > NNODES - 1) n = NNODES - 1;
            As[k][m] = x[(size_t)n * F + k];
        }
        for (int idx = tid; idx < F * 64; idx += 256)
            Ws[idx >> 6][idx & 63] = root[idx];
    }
    __syncthreads();
    gemm_acc<F>(As, Ws, r, c, acc);

    // ---- phase 2c (L0 only): res_w pass (As preserved = x tile) ----
    if (L0) {
        __syncthreads();
        for (int idx = tid; idx < F * 64; idx += 256)
            Ws[idx >> 6][idx & 63] = resw[idx];
        __syncthreads();
        gemm_acc<F>(As, Ws, r, c, accB);
    }

    // ---- epilogue ----
    const float4 bv = *(const float4*)&bias[c * 4];
    const float4 gv = *(const float4*)&lng[c * 4];
    const float4 be = *(const float4*)&lnb[c * 4];
    const float b_[4] = {bv.x, bv.y, bv.z, bv.w};
    const float g_[4] = {gv.x, gv.y, gv.z, gv.w};
    const float e_[4] = {be.x, be.y, be.z, be.w};
    float s2_[4] = {0.f, 0.f, 0.f, 0.f};
    if (L0) {
        const float4 sv = *(const float4*)&resb[c * 4];
        s2_[0] = sv.x; s2_[1] = sv.y; s2_[2] = sv.z; s2_[3] = sv.w;
    }
    #pragma unroll
    for (int i = 0; i < 4; ++i) {
        int n = nbase + r * 4 + i;
        int nc = n > NNODES - 1 ? NNODES - 1 : n;
        float u[4];
        float s = 0.f;
        if (L0) {
            #pragma unroll
            for (int j = 0; j < 4; ++j) {
                u[j] = fmaxf(acc[i][j] + b_[j], 0.f) + accB[i][j] + s2_[j];
                s += u[j];
            }
        } else {
            const float4 rv = *(const float4*)&x[(size_t)nc * 64 + c * 4];
            const float r_[4] = {rv.x, rv.y, rv.z, rv.w};
            #pragma unroll
            for (int j = 0; j < 4; ++j) {
                u[j] = fmaxf(acc[i][j] + b_[j], 0.f) + r_[j];
                s += u[j];
            }
        }
        ln_group_reduce(s);
        float mu = s * (1.f / 64.f);
        float q = 0.f;
        #pragma unroll
        for (int j = 0; j < 4; ++j) { u[j] -= mu; q += u[j] * u[j]; }
        ln_group_reduce(q);
        float inv = 1.f / sqrtf(q * (1.f / 64.f) + 1e-5f);
        if (n < NNODES) {
            float o[4];
            #pragma unroll
            for (int j = 0; j < 4; ++j) o[j] = u[j] * inv * g_[j] + e_[j];
            if (POOL) {
                int g = batch[n];
                #pragma unroll
                for (int j = 0; j < 4; ++j)
                    atomicAdd(dst + (size_t)g * 64 + c * 4 + j, o[j]);
            } else {
                *(float4*)&dst[(size_t)n * 64 + c * 4] =
                    make_float4(o[0], o[1], o[2], o[3]);
            }
        }
    }
}

// ---------------------------------------------------------------------------
// readout: out[g] = relu(pooled[g]/cnt @ ro_w1 + ro_b1) @ ro_w2 + ro_b2
// ---------------------------------------------------------------------------
__global__ __launch_bounds__(256) void readout_kernel(
    const float* __restrict__ pooled, const int* __restrict__ gcnt,
    const float* __restrict__ w1, const float* __restrict__ b1,
    const float* __restrict__ w2, const float* __restrict__ b2,
    float* __restrict__ out) {
    __shared__ float wl[64][64];
    int tid = threadIdx.x;
    for (int idx = tid; idx < 64 * 64; idx += 256) {
        wl[idx >> 6][idx & 63] = w1[idx];
    }
    __syncthreads();
    int wv = tid >> 6, lane = tid & 63;
    int g = blockIdx.x * 4 + wv;
    if (g >= NGRAPH) return;
    int cc = gcnt[g];
    float cf = cc > 0 ? (float)cc : 1.0f;
    float p = pooled[(size_t)g * 64 + lane] / cf;
    float acc = b1[lane];
    for (int f = 0; f < 64; ++f) {
        acc += __shfl(p, f) * wl[f][lane];
    }
    float t = fmaxf(acc, 0.f);
    float v = t * w2[lane];
    #pragma unroll
    for (int o = 32; o; o >>= 1) v += __shfl_xor(v, o);
    if (lane == 0) out[g] = v + b2[0];
}

// ---------------------------------------------------------------------------
extern "C" void kernel_launch(void* const* d_in, const int* in_sizes, int n_in,
                              void* d_out, int out_size, void* d_ws, size_t ws_size,
                              hipStream_t stream) {
    const float* x     = (const float*)d_in[0];
    const int*   ei    = (const int*)d_in[1];
    const int*   et    = (const int*)d_in[2];
    const int*   batch = (const int*)d_in[3];
    const float* W0    = (const float*)d_in[4];
    const float* root0 = (const float*)d_in[5];
    const float* b0    = (const float*)d_in[6];
    const float* ln0g  = (const float*)d_in[7];
    const float* ln0b  = (const float*)d_in[8];
    const float* resw  = (const float*)d_in[9];
    const float* resb  = (const float*)d_in[10];
    const float* W1    = (const float*)d_in[11];
    const float* root1 = (const float*)d_in[12];
    const float* b1    = (const float*)d_in[13];
    const float* ln1g  = (const float*)d_in[14];
    const float* ln1b  = (const float*)d_in[15];
    const float* W2    = (const float*)d_in[16];
    const float* root2 = (const float*)d_in[17];
    const float* b2    = (const float*)d_in[18];
    const float* ln2g  = (const float*)d_in[19];
    const float* ln2b  = (const float*)d_in[20];
    const float* row1  = (const float*)d_in[21];
    const float* rob1  = (const float*)d_in[22];
    const float* row2  = (const float*)d_in[23];
    const float* rob2  = (const float*)d_in[24];
    float* out = (float*)d_out;

    char* ws = (char*)d_ws;
    size_t off = 0;
    int* cnt    = (int*)(ws + off); off += (size_t)NSEG * 4;            // 1.6 MB
    int* fill   = (int*)(ws + off); off += (size_t)NSEG * 4;            // 1.6 MB
    int* gcnt   = (int*)(ws + off); off += 4096;
    float* pooled = (float*)(ws + off); off += (size_t)NGRAPH * 64 * 4; // 256 KB
    size_t zero_bytes = off;                                            // ~3.46 MB
    int* excl   = (int*)(ws + off); off += (size_t)NSEG * 4;
    int* bsum   = (int*)(ws + off); off += 4096;
    int* esrc   = (int*)(ws + off); off += (size_t)NEDGES * 4;          // 6.4 MB
    float* xA   = (float*)(ws + off); off += (size_t)NNODES * 64 * 4;   // 25.6 MB
    float* xB   = (float*)(ws + off); off += (size_t)NNODES * 64 * 4;   // 25.6 MB

    hipMemsetAsync(d_ws, 0, zero_bytes, stream);

    count_kernel<<<6250, 256, 0, stream>>>(ei, et, batch, cnt, gcnt);
    scan1_kernel<<<NSCANB, 256, 0, stream>>>(cnt, excl, bsum);
    scan2_kernel<<<1, 512, 0, stream>>>(bsum);
    place_kernel<<<6250, 256, 0, stream>>>(ei, et, excl, bsum, fill, esrc);

    const int GBLK = (NNODES + 63) / 64;   // 1563

    // ---- layer 0: x[38] -> xA ----
    fused_kernel<DIN, true, false><<<GBLK, 256, 0, stream>>>(
        x, W0, root0, resw, b0, resb, ln0g, ln0b,
        cnt, excl, bsum, esrc, batch, xA);

    // ---- layer 1: xA -> xB ----
    fused_kernel<HID, false, false><<<GBLK, 256, 0, stream>>>(
        xA, W1, root1, nullptr, b1, resb, ln1g, ln1b,
        cnt, excl, bsum, esrc, batch, xB);

    // ---- layer 2: xB -> pooled (fused mean-pool atomics) ----
    fused_kernel<HID, false, true><<<GBLK, 256, 0, stream>>>(
        xB, W2, root2, nullptr, b2, resb, ln2g, ln2b,
        cnt, excl, bsum, esrc, batch, pooled);

    // ---- readout ----
    readout_kernel<<<250, 256, 0, stream>>>(
        pooled, gcnt, row1, rob1, row2, rob2, out);
}

// Round 6
// 767.404 us; speedup vs baseline: 1.6839x; 1.6839x over previous
//
#include <hip/hip_runtime.h>
#include <math.h>

#define NNODES 100000
#define NEDGES 1600000
#define NREL   4
#define DIN    38
#define HID    64
#define NGRAPH 1000
#define NSEG   (NNODES * NREL)          // 400000
#define NSCANB ((NSEG + 1023) / 1024)   // 391
#define YW     320                      // y row width (4 rel slices + root slice)

__device__ __forceinline__ float wsum64(float v) {
    #pragma unroll
    for (int o = 32; o; o >>= 1) v += __shfl_xor(v, o);
    return v;
}

__device__ __forceinline__ void ln_group_reduce(float& s) {
    s += __shfl_xor(s, 1);
    s += __shfl_xor(s, 2);
    s += __shfl_xor(s, 4);
    s += __shfl_xor(s, 8);
}

// ---------------------------------------------------------------------------
// counts: cnt[node*R+rel] edge counts, gcnt[g] nodes per graph
// ---------------------------------------------------------------------------
__global__ __launch_bounds__(256) void count_kernel(
    const int* __restrict__ ei, const int* __restrict__ et,
    const int* __restrict__ batch, int* __restrict__ cnt,
    int* __restrict__ gcnt) {
    int i = blockIdx.x * 256 + threadIdx.x;
    if (i < NEDGES) {
        int dst = ei[NEDGES + i];
        atomicAdd(&cnt[dst * NREL + et[i]], 1);
    }
    if (i < NNODES) {
        atomicAdd(&gcnt[batch[i]], 1);
    }
}

// ---------------------------------------------------------------------------
// scan1: per-1024-chunk exclusive scan of cnt -> excl, chunk totals -> bsum
// ---------------------------------------------------------------------------
__global__ __launch_bounds__(256) void scan1_kernel(
    const int* __restrict__ cnt, int* __restrict__ excl, int* __restrict__ bsum) {
    __shared__ int tmp[256];
    int tid = threadIdx.x;
    int base = blockIdx.x * 1024 + tid * 4;
    int v0 = 0, v1 = 0, v2 = 0, v3 = 0;
    if (base + 0 < NSEG) v0 = cnt[base + 0];
    if (base + 1 < NSEG) v1 = cnt[base + 1];
    if (base + 2 < NSEG) v2 = cnt[base + 2];
    if (base + 3 < NSEG) v3 = cnt[base + 3];
    int s = v0 + v1 + v2 + v3;
    tmp[tid] = s;
    __syncthreads();
    for (int off = 1; off < 256; off <<= 1) {
        int t = (tid >= off) ? tmp[tid - off] : 0;
        __syncthreads();
        tmp[tid] += t;
        __syncthreads();
    }
    if (tid == 255) bsum[blockIdx.x] = tmp[255];
    int run = tmp[tid] - s;
    if (base + 0 < NSEG) excl[base + 0] = run; run += v0;
    if (base + 1 < NSEG) excl[base + 1] = run; run += v1;
    if (base + 2 < NSEG) excl[base + 2] = run; run += v2;
    if (base + 3 < NSEG) excl[base + 3] = run;
}

// scan2: exclusive scan of bsum[NSCANB] in one block
__global__ __launch_bounds__(512) void scan2_kernel(int* __restrict__ bsum) {
    __shared__ int tmp[512];
    int tid = threadIdx.x;
    int v = (tid < NSCANB) ? bsum[tid] : 0;
    tmp[tid] = v;
    __syncthreads();
    for (int off = 1; off < 512; off <<= 1) {
        int t = (tid >= off) ? tmp[tid - off] : 0;
        __syncthreads();
        tmp[tid] += t;
        __syncthreads();
    }
    if (tid < NSCANB) bsum[tid] = tmp[tid] - v;
}

// ---------------------------------------------------------------------------
// place: CSR bucket fill. packed entry = src | (rel << 20)
// ---------------------------------------------------------------------------
__global__ __launch_bounds__(256) void place_kernel(
    const int* __restrict__ ei, const int* __restrict__ et,
    const int* __restrict__ excl, const int* __restrict__ bsum,
    int* __restrict__ fill, int* __restrict__ esrc) {
    int e = blockIdx.x * 256 + threadIdx.x;
    if (e >= NEDGES) return;
    int r = et[e];
    int seg = ei[NEDGES + e] * NREL + r;
    int pos = excl[seg] + bsum[seg >> 10] + atomicAdd(&fill[seg], 1);
    esrc[pos] = ei[e] | (r << 20);
}

// ---------------------------------------------------------------------------
// gemm12: y[n][nc*64+ch] = sum_k x[n][k] * B[k][gc],  B = [W_r0..W_r3 | root]
// ---------------------------------------------------------------------------
__global__ __launch_bounds__(256, 4) void gemm12_kernel(
    const float* __restrict__ x, const float* __restrict__ W,
    const float* __restrict__ root, float* __restrict__ y) {
    __shared__ float As[64][68];
    __shared__ float Ws[64][68];
    int tid = threadIdx.x;
    int nbase = blockIdx.x * 64;

    {   // stage As (full K=64)
        int sk = tid & 63, sm0 = tid >> 6;
        #pragma unroll
        for (int mm = 0; mm < 16; ++mm) {
            int m = sm0 + mm * 4;
            int n = nbase + m; if (n > NNODES - 1) n = NNODES - 1;
            As[sk][m] = x[(size_t)n * 64 + sk];
        }
    }
    int r = tid >> 4, c = tid & 15;
    int scc = tid & 63, sk0 = tid >> 6;

    for (int nc = 0; nc < 5; ++nc) {
        __syncthreads();
        const float* src = (nc < 4) ? (W + nc * 4096) : root;
        #pragma unroll
        for (int kk = 0; kk < 16; ++kk) {
            int k = sk0 + kk * 4;
            Ws[k][scc] = src[k * 64 + scc];
        }
        __syncthreads();
        float acc[4][4] = {};
        #pragma unroll 4
        for (int k = 0; k < 64; ++k) {
            const float4 av = *(const float4*)&As[k][r * 4];
            const float4 wv = *(const float4*)&Ws[k][c * 4];
            const float a_[4] = {av.x, av.y, av.z, av.w};
            const float w_[4] = {wv.x, wv.y, wv.z, wv.w};
            #pragma unroll
            for (int i = 0; i < 4; ++i)
                #pragma unroll
                for (int j = 0; j < 4; ++j)
                    acc[i][j] += a_[i] * w_[j];
        }
        #pragma unroll
        for (int i = 0; i < 4; ++i) {
            int n = nbase + r * 4 + i;
            if (n < NNODES)
                *(float4*)&y[(size_t)n * YW + nc * 64 + c * 4] =
                    make_float4(acc[i][0], acc[i][1], acc[i][2], acc[i][3]);
        }
    }
}

// ---------------------------------------------------------------------------
// gemm0: x [N,38]; chunks 0-3: W0 slices, 4: root0 -> y[N,320];
//        chunk 5: res_w -> xres[N,64]
// ---------------------------------------------------------------------------
__global__ __launch_bounds__(256, 4) void gemm0_kernel(
    const float* __restrict__ x, const float* __restrict__ W0,
    const float* __restrict__ root0, const float* __restrict__ resw,
    float* __restrict__ y, float* __restrict__ xres) {
    __shared__ float As[38][68];
    __shared__ float Ws[38][68];
    int tid = threadIdx.x;
    int nbase = blockIdx.x * 64;

    for (int idx = tid; idx < 64 * 38; idx += 256) {
        int m = idx / 38, k = idx - m * 38;
        int n = nbase + m; if (n > NNODES - 1) n = NNODES - 1;
        As[k][m] = x[(size_t)n * DIN + k];
    }
    int r = tid >> 4, c = tid & 15;

    for (int nc = 0; nc < 6; ++nc) {
        __syncthreads();
        const float* src = (nc < 4) ? (W0 + nc * DIN * 64)
                                    : (nc == 4 ? root0 : resw);
        for (int idx = tid; idx < 38 * 64; idx += 256) {
            int k = idx >> 6, cc = idx & 63;
            Ws[k][cc] = src[idx];
        }
        __syncthreads();
        float acc[4][4] = {};
        #pragma unroll 2
        for (int k = 0; k < 38; ++k) {
            const float4 av = *(const float4*)&As[k][r * 4];
            const float4 wv = *(const float4*)&Ws[k][c * 4];
            const float a_[4] = {av.x, av.y, av.z, av.w};
            const float w_[4] = {wv.x, wv.y, wv.z, wv.w};
            #pragma unroll
            for (int i = 0; i < 4; ++i)
                #pragma unroll
                for (int j = 0; j < 4; ++j)
                    acc[i][j] += a_[i] * w_[j];
        }
        #pragma unroll
        for (int i = 0; i < 4; ++i) {
            int n = nbase + r * 4 + i;
            if (n < NNODES) {
                float4 o = make_float4(acc[i][0], acc[i][1], acc[i][2], acc[i][3]);
                if (nc < 5) *(float4*)&y[(size_t)n * YW + nc * 64 + c * 4] = o;
                else        *(float4*)&xres[(size_t)n * 64 + c * 4] = o;
            }
        }
    }
}

// ---------------------------------------------------------------------------
// epilogue: one wave per node, 4-edge-parallel gather.
// lane = (q = lane>>4: edge quarter, cl = lane&15: channel quarter).
// Staging (per 64-edge chunk): moff = src*5 + rel (y row-chunk index),
// ic = 1/max(cnt[rel],1) pre-scale (0 for invalid lanes). Inner loop:
// 2 shfls + 1 float4 load + 4 FMA per 4 edges. Cross-quarter shfl_xor
// reduce, then bias/ReLU/residual/LN epilogue (16-lane groups), q==0 stores.
// ---------------------------------------------------------------------------
template <bool L0, bool POOL>
__global__ __launch_bounds__(256) void epi_kernel(
    const float* __restrict__ y, const float* __restrict__ xprev,
    const int* __restrict__ esrc, const int* __restrict__ excl,
    const int* __restrict__ bsum, const int* __restrict__ cnt,
    const float* __restrict__ bias, const float* __restrict__ bias2,
    const float* __restrict__ lng, const float* __restrict__ lnb,
    const int* __restrict__ batch, float* __restrict__ dst) {
    int n = (blockIdx.x * 256 + threadIdx.x) >> 6;
    int lane = threadIdx.x & 63;
    if (n >= NNODES) return;
    int q = lane >> 4;        // edge quarter
    int cl = lane & 15;       // channel quarter

    int s4 = n * 4;
    int myc = 0, myb = 0;
    if (lane < 4) {
        myc = cnt[s4 + lane];
        myb = excl[s4 + lane] + bsum[(s4 + lane) >> 10];
    }
    float myi = 1.f / fmaxf((float)myc, 1.f);
    int c0 = __shfl(myc, 0), c1 = __shfl(myc, 1);
    int c2 = __shfl(myc, 2), c3 = __shfl(myc, 3);
    float i0 = __shfl(myi, 0), i1 = __shfl(myi, 1);
    float i2 = __shfl(myi, 2), i3 = __shfl(myi, 3);
    int beg = __shfl(myb, 0);
    int ctot = c0 + c1 + c2 + c3;

    float acc[4] = {0.f, 0.f, 0.f, 0.f};
    for (int base = 0; base < ctot; base += 64) {
        int rem = ctot - base; if (rem > 64) rem = 64;
        // stage: per-edge row-chunk offset + pre-scale factor
        int raw = (lane < rem) ? esrc[beg + base + lane] : 0;
        int src = raw & 0xFFFFF;
        int rel = raw >> 20;
        int moff = src * 5 + rel;
        float ic = (rel & 2) ? ((rel & 1) ? i3 : i2)
                             : ((rel & 1) ? i1 : i0);
        if (lane >= rem) ic = 0.f;

        int it = (rem + 3) >> 2;
        int i = 0;
        for (; i + 2 <= it; i += 2) {
            int l4a = i * 4 + q, l4b = l4a + 4;
            int offa = __shfl(moff, l4a);
            float ica = __shfl(ic, l4a);
            int offb = __shfl(moff, l4b);
            float icb = __shfl(ic, l4b);
            const float4 va = *(const float4*)&y[(size_t)offa * 64 + cl * 4];
            const float4 vb = *(const float4*)&y[(size_t)offb * 64 + cl * 4];
            acc[0] += va.x * ica; acc[1] += va.y * ica;
            acc[2] += va.z * ica; acc[3] += va.w * ica;
            acc[0] += vb.x * icb; acc[1] += vb.y * icb;
            acc[2] += vb.z * icb; acc[3] += vb.w * icb;
        }
        if (i < it) {
            int l4 = i * 4 + q;
            int off = __shfl(moff, l4);
            float icq = __shfl(ic, l4);
            const float4 v = *(const float4*)&y[(size_t)off * 64 + cl * 4];
            acc[0] += v.x * icq; acc[1] += v.y * icq;
            acc[2] += v.z * icq; acc[3] += v.w * icq;
        }
    }
    // combine edge quarters: all lanes end with full channel sums
    #pragma unroll
    for (int j = 0; j < 4; ++j) {
        acc[j] += __shfl_xor(acc[j], 16);
        acc[j] += __shfl_xor(acc[j], 32);
    }

    // epilogue (channels ch = cl*4+j; all quarters compute identically)
    const float4 yr = *(const float4*)&y[(size_t)n * YW + 256 + cl * 4];
    const float4 bv = *(const float4*)&bias[cl * 4];
    const float4 rv = *(const float4*)&xprev[(size_t)n * 64 + cl * 4];
    const float y_[4] = {yr.x, yr.y, yr.z, yr.w};
    const float b_[4] = {bv.x, bv.y, bv.z, bv.w};
    const float r_[4] = {rv.x, rv.y, rv.z, rv.w};
    float u[4];
    float s = 0.f;
    #pragma unroll
    for (int j = 0; j < 4; ++j) {
        u[j] = fmaxf(acc[j] + y_[j] + b_[j], 0.f) + r_[j];
        s += u[j];
    }
    if (L0) {
        const float4 sv = *(const float4*)&bias2[cl * 4];
        const float s2_[4] = {sv.x, sv.y, sv.z, sv.w};
        #pragma unroll
        for (int j = 0; j < 4; ++j) { u[j] += s2_[j]; s += s2_[j]; }
    }
    ln_group_reduce(s);
    float mu = s * (1.f / 64.f);
    float qq = 0.f;
    #pragma unroll
    for (int j = 0; j < 4; ++j) { u[j] -= mu; qq += u[j] * u[j]; }
    ln_group_reduce(qq);
    float inv = 1.f / sqrtf(qq * (1.f / 64.f) + 1e-5f);
    const float4 gv = *(const float4*)&lng[cl * 4];
    const float4 ev = *(const float4*)&lnb[cl * 4];
    const float g_[4] = {gv.x, gv.y, gv.z, gv.w};
    const float e_[4] = {ev.x, ev.y, ev.z, ev.w};
    float o[4];
    #pragma unroll
    for (int j = 0; j < 4; ++j) o[j] = u[j] * inv * g_[j] + e_[j];

    if (q == 0) {
        if (POOL) {
            int g = batch[n];
            #pragma unroll
            for (int j = 0; j < 4; ++j)
                atomicAdd(dst + (size_t)g * 64 + cl * 4 + j, o[j]);
        } else {
            *(float4*)&dst[(size_t)n * 64 + cl * 4] =
                make_float4(o[0], o[1], o[2], o[3]);
        }
    }
}

// ---------------------------------------------------------------------------
// readout: out[g] = relu(pooled[g]/cnt @ ro_w1 + ro_b1) @ ro_w2 + ro_b2
// ---------------------------------------------------------------------------
__global__ __launch_bounds__(256) void readout_kernel(
    const float* __restrict__ pooled, const int* __restrict__ gcnt,
    const float* __restrict__ w1, const float* __restrict__ b1,
    const float* __restrict__ w2, const float* __restrict__ b2,
    float* __restrict__ out) {
    __shared__ float wl[64][64];
    int tid = threadIdx.x;
    for (int idx = tid; idx < 64 * 64; idx += 256) {
        wl[idx >> 6][idx & 63] = w1[idx];
    }
    __syncthreads();
    int wv = tid >> 6, lane = tid & 63;
    int g = blockIdx.x * 4 + wv;
    if (g >= NGRAPH) return;
    int cc = gcnt[g];
    float cf = cc > 0 ? (float)cc : 1.0f;
    float p = pooled[(size_t)g * 64 + lane] / cf;
    float acc = b1[lane];
    for (int f = 0; f < 64; ++f) {
        acc += __shfl(p, f) * wl[f][lane];
    }
    float t = fmaxf(acc, 0.f);
    float v = t * w2[lane];
    v = wsum64(v);
    if (lane == 0) out[g] = v + b2[0];
}

// ---------------------------------------------------------------------------
extern "C" void kernel_launch(void* const* d_in, const int* in_sizes, int n_in,
                              void* d_out, int out_size, void* d_ws, size_t ws_size,
                              hipStream_t stream) {
    const float* x     = (const float*)d_in[0];
    const int*   ei    = (const int*)d_in[1];
    const int*   et    = (const int*)d_in[2];
    const int*   batch = (const int*)d_in[3];
    const float* W0    = (const float*)d_in[4];
    const float* root0 = (const float*)d_in[5];
    const float* b0    = (const float*)d_in[6];
    const float* ln0g  = (const float*)d_in[7];
    const float* ln0b  = (const float*)d_in[8];
    const float* resw  = (const float*)d_in[9];
    const float* resb  = (const float*)d_in[10];
    const float* W1    = (const float*)d_in[11];
    const float* root1 = (const float*)d_in[12];
    const float* b1    = (const float*)d_in[13];
    const float* ln1g  = (const float*)d_in[14];
    const float* ln1b  = (const float*)d_in[15];
    const float* W2    = (const float*)d_in[16];
    const float* root2 = (const float*)d_in[17];
    const float* b2    = (const float*)d_in[18];
    const float* ln2g  = (const float*)d_in[19];
    const float* ln2b  = (const float*)d_in[20];
    const float* row1  = (const float*)d_in[21];
    const float* rob1  = (const float*)d_in[22];
    const float* row2  = (const float*)d_in[23];
    const float* rob2  = (const float*)d_in[24];
    float* out = (float*)d_out;

    char* ws = (char*)d_ws;
    size_t off = 0;
    int* cnt    = (int*)(ws + off); off += (size_t)NSEG * 4;            // 1.6 MB
    int* fill   = (int*)(ws + off); off += (size_t)NSEG * 4;            // 1.6 MB
    int* gcnt   = (int*)(ws + off); off += 4096;
    float* pooled = (float*)(ws + off); off += (size_t)NGRAPH * 64 * 4; // 256 KB
    size_t zero_bytes = off;                                            // ~3.46 MB
    int* excl   = (int*)(ws + off); off += (size_t)NSEG * 4;
    int* bsum   = (int*)(ws + off); off += 4096;
    int* esrc   = (int*)(ws + off); off += (size_t)NEDGES * 4;          // 6.4 MB
    float* y    = (float*)(ws + off); off += (size_t)NNODES * YW * 4;   // 128 MB
    float* xA   = (float*)(ws + off); off += (size_t)NNODES * 64 * 4;   // 25.6 MB
    float* xB   = (float*)(ws + off); off += (size_t)NNODES * 64 * 4;   // 25.6 MB

    hipMemsetAsync(d_ws, 0, zero_bytes, stream);

    count_kernel<<<6250, 256, 0, stream>>>(ei, et, batch, cnt, gcnt);
    scan1_kernel<<<NSCANB, 256, 0, stream>>>(cnt, excl, bsum);
    scan2_kernel<<<1, 512, 0, stream>>>(bsum);
    place_kernel<<<6250, 256, 0, stream>>>(ei, et, excl, bsum, fill, esrc);

    const int GBLK = (NNODES + 63) / 64;   // 1563
    const int EBLK = (NNODES + 3) / 4;     // 25000

    // ---- layer 0 ----
    gemm0_kernel<<<GBLK, 256, 0, stream>>>(x, W0, root0, resw, y, xA);
    epi_kernel<true, false><<<EBLK, 256, 0, stream>>>(
        y, xA, esrc, excl, bsum, cnt, b0, resb, ln0g, ln0b, batch, xA);

    // ---- layer 1 ----
    gemm12_kernel<<<GBLK, 256, 0, stream>>>(xA, W1, root1, y);
    epi_kernel<false, false><<<EBLK, 256, 0, stream>>>(
        y, xA, esrc, excl, bsum, cnt, b1, resb, ln1g, ln1b, batch, xB);

    // ---- layer 2 (pool fused) ----
    gemm12_kernel<<<GBLK, 256, 0, stream>>>(xB, W2, root2, y);
    epi_kernel<false, true><<<EBLK, 256, 0, stream>>>(
        y, xB, esrc, excl, bsum, cnt, b2, resb, ln2g, ln2b, batch, pooled);

    // ---- readout ----
    readout_kernel<<<250, 256, 0, stream>>>(
        pooled, gcnt, row1, rob1, row2, rob2, out);
}